// Round 1
// baseline (191.856 us; speedup 1.0000x reference)
//
#include <hip/hip_runtime.h>

#define EPS_F 1e-7f
#define BONUS 10.0f

// One thread computes 4 consecutive-w voxels from a 3(d) x 3(h) x 6(w) register
// window. Per row: 1x dwordx4 + 2 edge dwords (vs 12 scalar loads before).
// Solve is fully scalarized (no runtime-indexed arrays -> no scratch), with
// the exact same pivoting and arithmetic order as the previously verified kernel.
__global__ __launch_bounds__(256) void quadinterp3d_kernel(
    const float* __restrict__ x, const float* __restrict__ noise,
    float* __restrict__ out, int B, int D, int H, int W)
{
    const int d = blockIdx.x;
    const int h = blockIdx.y;
    const int b = blockIdx.z;
    const int w0 = (int)threadIdx.x * 4;   // block covers the full W=1024 row

    const int HW  = H * W;
    const int DHW = D * HW;

    const int dm = max(d - 1, 0), dp = min(d + 1, D - 1);
    const int hm = max(h - 1, 0), hp = min(h + 1, H - 1);
    const int wl = max(w0 - 1, 0);
    const int wr = min(w0 + 4, W - 1);

    const float* base = x + (size_t)b * DHW;
    const int doffs[3] = { dm * HW, d * HW, dp * HW };
    const int hoffs[3] = { hm * W,  h * W,  hp * W  };

    // [left | c0 c1 c2 c3 | right] per (d,h) row
    float r[3][3][6];
#pragma unroll
    for (int i = 0; i < 3; ++i) {
#pragma unroll
        for (int j = 0; j < 3; ++j) {
            const float* p = base + (doffs[i] + hoffs[j]);
            const float4 cv = *reinterpret_cast<const float4*>(p + w0);
            r[i][j][0] = p[wl];
            r[i][j][1] = cv.x;
            r[i][j][2] = cv.y;
            r[i][j][3] = cv.z;
            r[i][j][4] = cv.w;
            r[i][j][5] = p[wr];
        }
    }

    const float n0 = noise[0]*EPS_F, n1 = noise[1]*EPS_F, n2 = noise[2]*EPS_F;
    const float n3 = noise[3]*EPS_F, n4 = noise[4]*EPS_F, n5 = noise[5]*EPS_F;
    const float n6 = noise[6]*EPS_F, n7 = noise[7]*EPS_F, n8 = noise[8]*EPS_F;

    // Column maxima over the 9 (d,h) rows, shared by the 4 voxels.
    float colmax[6];
#pragma unroll
    for (int k = 0; k < 6; ++k) {
        float m = r[0][0][k];
#pragma unroll
        for (int i = 0; i < 3; ++i)
#pragma unroll
            for (int j = 0; j < 3; ++j) m = fmaxf(m, r[i][j][k]);
        colmax[k] = m;
    }

    float od0[4], od1[4], od2[4], oyv[4];

#pragma unroll
    for (int q = 0; q < 4; ++q) {
        const float c = r[1][1][q + 1];

        // gradients (kornia diff mode; depth kernel flipped -> gz sign)
        const float gx = 0.5f * (r[1][1][q+2] - r[1][1][q]);
        const float gy = 0.5f * (r[1][2][q+1] - r[1][0][q+1]);
        const float gz = 0.5f * (r[0][1][q+1] - r[2][1][q+1]);

        // second-order
        const float dxx = r[1][1][q+2] - 2.0f * c + r[1][1][q];
        const float dyy = r[1][2][q+1] - 2.0f * c + r[1][0][q+1];
        const float dss = r[2][1][q+1] - 2.0f * c + r[0][1][q+1];
        const float dxy = 0.25f * (r[1][0][q] - r[1][0][q+2] - r[1][2][q] + r[1][2][q+2]);
        const float dys = 0.25f * (r[2][0][q+1] - r[2][2][q+1] - r[0][0][q+1] + r[0][2][q+1]);
        const float dxs = 0.25f * (r[2][1][q] - r[2][1][q+2] - r[0][1][q] + r[0][1][q+2]);

        // strict NMS: c is the max of the (clamped) 27-neighborhood
        const float mx = fmaxf(fmaxf(colmax[q], colmax[q+1]), colmax[q+2]);
        const bool mask = (c == mx);

        float dx0 = 0.0f, dx1 = 0.0f, dx2 = 0.0f, dy = 0.0f;
        if (mask) {
            // Hessian + asymmetric noise guard
            const float A00 = dxx + n0, A01 = dxy + n1, A02 = dxs + n2;
            const float A10 = dxy + n3, A11 = dyy + n4, A12 = dys + n5;
            const float A20 = dxs + n6, A21 = dys + n7, A22 = dss + n8;
            const float r0 = gx, r1 = gy, r2 = gz;

            // column-0 partial pivot (LAPACK gesv order), branch-free selects
            const float a0 = fabsf(A00), a1 = fabsf(A10), a2 = fabsf(A20);
            const bool p2 = a2 > fmaxf(a0, a1);
            const bool p1 = (a1 > a0) && !p2;

            const float t00 = p1 ? A10 : (p2 ? A20 : A00);
            const float t01 = p1 ? A11 : (p2 ? A21 : A01);
            const float t02 = p1 ? A12 : (p2 ? A22 : A02);
            const float tr0 = p1 ? r1  : (p2 ? r2  : r0);
            const float u10 = p1 ? A00 : A10;
            const float u11 = p1 ? A01 : A11;
            const float u12 = p1 ? A02 : A12;
            const float ur1 = p1 ? r0  : r1;
            const float u20 = p2 ? A00 : A20;
            const float u21 = p2 ? A01 : A21;
            const float u22 = p2 ? A02 : A22;
            const float ur2 = p2 ? r0  : r2;

            const float m1 = u10 / t00;
            const float m2 = u20 / t00;
            const float e11 = u11 - m1 * t01;
            const float e12 = u12 - m1 * t02;
            const float er1 = ur1 - m1 * tr0;
            const float e21 = u21 - m2 * t01;
            const float e22 = u22 - m2 * t02;
            const float er2 = ur2 - m2 * tr0;

            // column-1 partial pivot
            const bool q2 = fabsf(e21) > fabsf(e11);
            const float f11 = q2 ? e21 : e11;
            const float f12 = q2 ? e22 : e12;
            const float fr1 = q2 ? er2 : er1;
            const float g21 = q2 ? e11 : e21;
            const float g22 = q2 ? e12 : e22;
            const float gr2 = q2 ? er1 : er2;

            const float mm  = g21 / f11;
            const float h22 = g22 - mm * f12;
            const float hr2 = gr2 - mm * fr1;

            // back substitution
            const float s2 = hr2 / h22;
            const float s1 = (fr1 - f12 * s2) / f11;
            const float s0 = (tr0 - t01 * s1 - t02 * s2) / t00;

            dx0 = -s0; dx1 = -s1; dx2 = -s2;
            const float amax = fmaxf(fabsf(dx0), fmaxf(fabsf(dx1), fabsf(dx2)));
            if (amax > 0.7f) { dx0 = 0.0f; dx1 = 0.0f; dx2 = 0.0f; }
            dy = 0.5f * (gx * dx0 + gy * dx1 + gz * dx2);
        }

        od0[q] = (float)d + dx2;
        od1[q] = (float)h + dx1;
        od2[q] = (float)(w0 + q) + dx0;
        oyv[q] = c + dy + (mask ? BONUS : 0.0f);
    }

    const size_t spatial = (size_t)d * HW + (size_t)h * W + w0;
    float* oc = out + (size_t)b * 3 * DHW + spatial;
    *reinterpret_cast<float4*>(oc)                   = make_float4(od0[0], od0[1], od0[2], od0[3]);
    *reinterpret_cast<float4*>(oc + DHW)             = make_float4(od1[0], od1[1], od1[2], od1[3]);
    *reinterpret_cast<float4*>(oc + 2 * (size_t)DHW) = make_float4(od2[0], od2[1], od2[2], od2[3]);
    float* oy = out + (size_t)B * 3 * DHW + (size_t)b * DHW + spatial;
    *reinterpret_cast<float4*>(oy)                   = make_float4(oyv[0], oyv[1], oyv[2], oyv[3]);
}

extern "C" void kernel_launch(void* const* d_in, const int* in_sizes, int n_in,
                              void* d_out, int out_size, void* d_ws, size_t ws_size,
                              hipStream_t stream) {
    const float* x     = (const float*)d_in[0];
    const float* noise = (const float*)d_in[1];
    float* out = (float*)d_out;

    const int B = 2, D = 4, H = 1024, W = 1024;

    dim3 block(256, 1, 1);                 // 256 threads x 4 voxels = full W row
    dim3 grid(D, H, B);
    quadinterp3d_kernel<<<grid, block, 0, stream>>>(x, noise, out, B, D, H, W);
}

// Round 2
// 186.713 us; speedup vs baseline: 1.0275x; 1.0275x over previous
//
#include <hip/hip_runtime.h>

#define EPS_F 1e-7f
#define BONUS 10.0f

// One voxel per thread (verified-fastest structure, ~24 us kernel time:
// write-bound at ~6.7 TB/s on the 134 MB output; input is L3-resident).
// Outputs stored non-temporally: never re-read, so keep them out of L2/L3
// to preserve input residency across iterations.
__global__ __launch_bounds__(256) void quadinterp3d_kernel(
    const float* __restrict__ x, const float* __restrict__ noise,
    float* __restrict__ out, int B, int D, int H, int W)
{
    int w = blockIdx.x * blockDim.x + threadIdx.x;
    int h = blockIdx.y;
    int bd = blockIdx.z;
    int d = bd % D;
    int b = bd / D;
    if (w >= W) return;

    const long long HW  = (long long)H * W;
    const long long DHW = (long long)D * HW;

    int wm = max(w - 1, 0), wp = min(w + 1, W - 1);
    int hm = max(h - 1, 0), hp = min(h + 1, H - 1);
    int dm = max(d - 1, 0), dp = min(d + 1, D - 1);

    const float* base = x + (long long)b * DHW;

    int ds[3] = {dm, d, dp};
    int hs[3] = {hm, h, hp};
    int wsx[3] = {wm, w, wp};

    float v[3][3][3];
#pragma unroll
    for (int i = 0; i < 3; ++i) {
#pragma unroll
        for (int j = 0; j < 3; ++j) {
            const float* row = base + (long long)ds[i] * HW + (long long)hs[j] * W;
#pragma unroll
            for (int k = 0; k < 3; ++k) v[i][j][k] = row[wsx[k]];
        }
    }

    float c = v[1][1][1];

    // gradients (kornia diff mode; depth kernel flipped -> gz sign)
    float gx = 0.5f * (v[1][1][2] - v[1][1][0]);
    float gy = 0.5f * (v[1][2][1] - v[1][0][1]);
    float gz = 0.5f * (v[0][1][1] - v[2][1][1]);

    // second-order
    float dxx = v[1][1][2] - 2.0f * c + v[1][1][0];
    float dyy = v[1][2][1] - 2.0f * c + v[1][0][1];
    float dss = v[2][1][1] - 2.0f * c + v[0][1][1];
    float dxy = 0.25f * (v[1][0][0] - v[1][0][2] - v[1][2][0] + v[1][2][2]);
    float dys = 0.25f * (v[2][0][1] - v[2][2][1] - v[0][0][1] + v[0][2][1]);
    float dxs = 0.25f * (v[2][1][0] - v[2][1][2] - v[0][1][0] + v[0][1][2]);

    // strict-NMS: c is the max of the (clamped) 27-neighborhood.
    float mx27 = c;
#pragma unroll
    for (int i = 0; i < 3; ++i)
#pragma unroll
        for (int j = 0; j < 3; ++j)
#pragma unroll
            for (int k = 0; k < 3; ++k) mx27 = fmaxf(mx27, v[i][j][k]);
    bool mask = (c == mx27);

    float dx0 = 0.0f, dx1 = 0.0f, dx2 = 0.0f, dy = 0.0f;

    if (mask) {
        // Hessian + asymmetric noise guard
        float A[3][3];
        float rhs[3];
        A[0][0] = dxx + noise[0] * EPS_F;
        A[0][1] = dxy + noise[1] * EPS_F;
        A[0][2] = dxs + noise[2] * EPS_F;
        A[1][0] = dxy + noise[3] * EPS_F;
        A[1][1] = dyy + noise[4] * EPS_F;
        A[1][2] = dys + noise[5] * EPS_F;
        A[2][0] = dxs + noise[6] * EPS_F;
        A[2][1] = dys + noise[7] * EPS_F;
        A[2][2] = dss + noise[8] * EPS_F;
        rhs[0] = gx; rhs[1] = gy; rhs[2] = gz;

        // 3x3 Gaussian elimination w/ partial pivoting (LAPACK gesv order)
        // column 0 pivot
        {
            int p = 0; float am = fabsf(A[0][0]);
            if (fabsf(A[1][0]) > am) { am = fabsf(A[1][0]); p = 1; }
            if (fabsf(A[2][0]) > am) { p = 2; }
            if (p != 0) {
#pragma unroll
                for (int j = 0; j < 3; ++j) { float t = A[0][j]; A[0][j] = A[p][j]; A[p][j] = t; }
                float t = rhs[0]; rhs[0] = rhs[p]; rhs[p] = t;
            }
            float m1 = A[1][0] / A[0][0];
            float m2 = A[2][0] / A[0][0];
            A[1][1] -= m1 * A[0][1]; A[1][2] -= m1 * A[0][2]; rhs[1] -= m1 * rhs[0];
            A[2][1] -= m2 * A[0][1]; A[2][2] -= m2 * A[0][2]; rhs[2] -= m2 * rhs[0];
        }
        // column 1 pivot
        {
            if (fabsf(A[2][1]) > fabsf(A[1][1])) {
                float t;
                t = A[1][1]; A[1][1] = A[2][1]; A[2][1] = t;
                t = A[1][2]; A[1][2] = A[2][2]; A[2][2] = t;
                t = rhs[1]; rhs[1] = rhs[2]; rhs[2] = t;
            }
            float m = A[2][1] / A[1][1];
            A[2][2] -= m * A[1][2]; rhs[2] -= m * rhs[1];
        }
        // back substitution
        float s2 = rhs[2] / A[2][2];
        float s1 = (rhs[1] - A[1][2] * s2) / A[1][1];
        float s0 = (rhs[0] - A[0][1] * s1 - A[0][2] * s2) / A[0][0];

        dx0 = -s0; dx1 = -s1; dx2 = -s2;
        float amax = fmaxf(fabsf(dx0), fmaxf(fabsf(dx1), fabsf(dx2)));
        if (amax > 0.7f) { dx0 = 0.0f; dx1 = 0.0f; dx2 = 0.0f; }
        dy = 0.5f * (gx * dx0 + gy * dx1 + gz * dx2);
    }

    long long spatial = (long long)d * HW + (long long)h * W + w;
    // coords_max: (B, C=1, 3, D, H, W); channel order (d,h,w) = dx[::-1]
    float* oc = out + (long long)b * 3 * DHW + spatial;
    __builtin_nontemporal_store((float)d + dx2, oc);
    __builtin_nontemporal_store((float)h + dx1, oc + DHW);
    __builtin_nontemporal_store((float)w + dx0, oc + 2 * DHW);
    // y_max: after all coords
    float* oy = out + (long long)B * 3 * DHW + (long long)b * DHW + spatial;
    __builtin_nontemporal_store(c + dy + (mask ? BONUS : 0.0f), oy);
}

extern "C" void kernel_launch(void* const* d_in, const int* in_sizes, int n_in,
                              void* d_out, int out_size, void* d_ws, size_t ws_size,
                              hipStream_t stream) {
    const float* x     = (const float*)d_in[0];
    const float* noise = (const float*)d_in[1];
    float* out = (float*)d_out;

    const int B = 2, D = 4, H = 1024, W = 1024;

    dim3 block(256, 1, 1);
    dim3 grid(W / 256, H, B * D);
    quadinterp3d_kernel<<<grid, block, 0, stream>>>(x, noise, out, B, D, H, W);
}